// Round 4
// baseline (116.106 us; speedup 1.0000x reference)
//
#include <hip/hip_runtime.h>
#include <hip/hip_bf16.h>

namespace {

constexpr int MM = 64;
constexpr int KK = 4096;
constexpr int NN = 11008;
constexpr int NZROW = NN / 8;     // 1376
constexpr int BN = 128;           // cols per block tile
constexpr int KSPLIT = 8;
constexpr int KSEG = KK / KSPLIT; // 512
constexpr int NTILES = NN / BN;   // 86
constexpr int BK = 32;            // k per chunk (one MFMA K)
constexpr int RS = 20;            // LDS row stride in int32 (16 data + 4 pad; rows stay 16B aligned)

typedef float f32x4 __attribute__((ext_vector_type(4)));
typedef short s16x8 __attribute__((ext_vector_type(8)));
typedef int   i32x4 __attribute__((ext_vector_type(4)));

__device__ __forceinline__ int pack_bf16(float a, float b) {
  union { __hip_bfloat162 h; int i; } u;
  u.h.x = __float2bfloat16(a);
  u.h.y = __float2bfloat16(b);
  return u.i;
}

// out[m][n] = bias[n]  (K-split partials atomicAdd on top)
__global__ __launch_bounds__(256) void prep_kernel(
    const float* __restrict__ bias, float* __restrict__ out)
{
  const int i = blockIdx.x * 256 + threadIdx.x;
  out[i] = bias[i % NN];
}

// Block = 256 thr = 4 waves; tile = 64 rows x 128 cols; K split 8 ways.
// B tile dequantized EXACTLY during staging:
//   qf = float(8388608 + q) via (nib | 0x4B000000)   [ulp=1 at 2^23 — q in
//   integer-exact mantissa bits]
//   d  = qf - float(8388608 + z + 1)                 [Sterbenz-exact: q-z-1]
//   W  = s * d                                       [single rounding]
// then bf16-packed. Plain m97-style bf16 MFMA GEMM — no offset tricks.
__global__ __launch_bounds__(256, 2) void gptq_gemm_kernel(
    const float* __restrict__ x, const int* __restrict__ qw,
    const int* __restrict__ qz, const float* __restrict__ scales,
    float* __restrict__ out)
{
  __shared__ int As[MM * RS];    // 5120 B  x tile, bf16 pairs, k-contiguous
  __shared__ int Bs[BN * RS];    // 10240 B dequantized W tile, bf16 pairs, k-contiguous

  const int tid  = threadIdx.x;
  const int wave = tid >> 6;
  const int lane = tid & 63;
  const int c    = lane & 15;    // A row-in-tile / B col-in-tile / D col
  const int quad = lane >> 4;

  const int ntile  = blockIdx.x % NTILES;
  const int ks     = blockIdx.x / NTILES;
  const int n0     = ntile * BN;
  const int kbase0 = ks * KSEG;

  const int am   = tid >> 2;     // A staging: row 0..63
  const int aseg = tid & 3;      // A staging: 8-k unit 0..3
  const int bu0  = tid >> 7;     // B staging: first 8-k unit (0 or 1)
  const int bn   = tid & 127;    // B staging: column 0..127
  const int mrow = wave * 16 + quad * 4;  // D rows = mrow..mrow+3

  f32x4 acc[8];
  #pragma unroll
  for (int t = 0; t < 8; ++t) acc[t] = {0.f, 0.f, 0.f, 0.f};

  for (int chunk = 0; chunk < KSEG / BK; ++chunk) {
    const int kc = kbase0 + chunk * BK;

    // ---- stage A: x fp32 -> bf16 pairs, natural k order ----
    const float* xp = x + am * KK + kc + aseg * 8;
    f32x4 f0 = *(const f32x4*)xp;
    f32x4 f1 = *(const f32x4*)(xp + 4);
    i32x4 pa;
    pa.x = pack_bf16(f0.x, f0.y);
    pa.y = pack_bf16(f0.z, f0.w);
    pa.z = pack_bf16(f1.x, f1.y);
    pa.w = pack_bf16(f1.z, f1.w);
    *(i32x4*)&As[am * RS + aseg * 4] = pa;

    // ---- stage B: unpack + exact dequant + bf16 pack, natural k order ----
    // chunk is always inside one quant group (kc % 128 + 32 <= 128)
    const int g = kc >> 7;
    const int N = n0 + bn;
    const float s  = scales[g * NN + N];
    const int  zn  = (qz[g * NZROW + (N >> 3)] >> ((N & 7) * 4)) & 15;
    const float C  = (float)(0x800000 + zn + 1);  // 8388608 + z + 1, exact fp32
    const int r0 = kc >> 3;                       // qweight row base (4 rows/chunk)
    #pragma unroll
    for (int h = 0; h < 2; ++h) {
      const int u = bu0 + 2 * h;                  // 8-k unit 0..3
      const int v = qw[(r0 + u) * NN + N];
      float w0 = s * (__int_as_float(((v      ) & 15) | 0x4B000000) - C);
      float w1 = s * (__int_as_float(((v >>  4) & 15) | 0x4B000000) - C);
      float w2 = s * (__int_as_float(((v >>  8) & 15) | 0x4B000000) - C);
      float w3 = s * (__int_as_float(((v >> 12) & 15) | 0x4B000000) - C);
      float w4 = s * (__int_as_float(((v >> 16) & 15) | 0x4B000000) - C);
      float w5 = s * (__int_as_float(((v >> 20) & 15) | 0x4B000000) - C);
      float w6 = s * (__int_as_float(((v >> 24) & 15) | 0x4B000000) - C);
      float w7 = s * (__int_as_float(((v >> 28) & 15) | 0x4B000000) - C);
      i32x4 pb;
      pb.x = pack_bf16(w0, w1);
      pb.y = pack_bf16(w2, w3);
      pb.z = pack_bf16(w4, w5);
      pb.w = pack_bf16(w6, w7);
      *(i32x4*)&Bs[bn * RS + u * 4] = pb;
    }

    __syncthreads();

    // ---- fragments + 8 MFMAs (16x16x32 bf16), m97-verified layout ----
    const s16x8 af = *(const s16x8*)&As[(wave * 16 + c) * RS + quad * 4];
    #pragma unroll
    for (int t = 0; t < 8; ++t) {
      const s16x8 bfr = *(const s16x8*)&Bs[(t * 16 + c) * RS + quad * 4];
      acc[t] = __builtin_amdgcn_mfma_f32_16x16x32_bf16(af, bfr, acc[t], 0, 0, 0);
    }

    __syncthreads();
  }

  // ---- epilogue: accumulate K-split partial into out (bias pre-loaded) ----
  #pragma unroll
  for (int t = 0; t < 8; ++t) {
    const int N = n0 + t * 16 + c;
    atomicAdd(&out[(mrow + 0) * NN + N], acc[t].x);
    atomicAdd(&out[(mrow + 1) * NN + N], acc[t].y);
    atomicAdd(&out[(mrow + 2) * NN + N], acc[t].z);
    atomicAdd(&out[(mrow + 3) * NN + N], acc[t].w);
  }
}

} // namespace

extern "C" void kernel_launch(void* const* d_in, const int* in_sizes, int n_in,
                              void* d_out, int out_size, void* d_ws, size_t ws_size,
                              hipStream_t stream) {
  const float* x      = (const float*)d_in[0];
  const int*   qw     = (const int*)d_in[1];
  const int*   qz     = (const int*)d_in[2];
  const float* scales = (const float*)d_in[3];
  const float* bias   = (const float*)d_in[4];
  float* out = (float*)d_out;

  prep_kernel<<<(MM * NN) / 256, 256, 0, stream>>>(bias, out);
  gptq_gemm_kernel<<<NTILES * KSPLIT, 256, 0, stream>>>(x, qw, qz, scales, out);
}

// Round 5
// 97.219 us; speedup vs baseline: 1.1943x; 1.1943x over previous
//
#include <hip/hip_runtime.h>
#include <hip/hip_bf16.h>

namespace {

constexpr int MM = 64;
constexpr int KK = 4096;
constexpr int NN = 11008;
constexpr int NZROW = NN / 8;     // 1376
constexpr int BN = 128;           // cols per block tile
constexpr int KSPLIT = 8;
constexpr int KSEG = KK / KSPLIT; // 512
constexpr int NTILES = NN / BN;   // 86
constexpr int BK = 32;            // k per chunk (one MFMA K)
constexpr int NCH = KSEG / BK;    // 16 chunks
constexpr int RS = 20;            // LDS row stride in int32 (16 data + 4 pad, rows 16B aligned)
constexpr int ABUF = MM * RS;     // 1280 int32 per buffer
constexpr int BBUF = BN * RS;     // 2560 int32 per buffer
constexpr size_t WS_NEED = (size_t)KSPLIT * MM * NN * 4;  // 22.5 MB partials

typedef float f32x4 __attribute__((ext_vector_type(4)));
typedef float f32x2 __attribute__((ext_vector_type(2)));
typedef short s16x8 __attribute__((ext_vector_type(8)));
typedef int   i32x4 __attribute__((ext_vector_type(4)));
typedef int   i32x2 __attribute__((ext_vector_type(2)));

__device__ __forceinline__ int pack_bf16(float a, float b) {
  union { __hip_bfloat162 h; int i; } u;
  u.h.x = __float2bfloat16(a);
  u.h.y = __float2bfloat16(b);
  return u.i;
}

// fallback path only: out[m][n] = bias[n], atomics on top
__global__ __launch_bounds__(256) void prep_kernel(
    const float* __restrict__ bias, float* __restrict__ out)
{
  const int i = blockIdx.x * 256 + threadIdx.x;
  out[i] = bias[i % NN];
}

// ws path: out = bias + sum of KSPLIT partials
__global__ __launch_bounds__(256) void reduce_kernel(
    const float* __restrict__ ws, const float* __restrict__ bias,
    float* __restrict__ out)
{
  const int i4 = (blockIdx.x * 256 + threadIdx.x) * 4;
  f32x4 acc = *(const f32x4*)(bias + (i4 % NN));   // i4, NN multiples of 4
  #pragma unroll
  for (int s = 0; s < KSPLIT; ++s)
    acc += *(const f32x4*)(ws + (size_t)s * (MM * NN) + i4);
  *(f32x4*)(out + i4) = acc;
}

// Pipelined GPTQ GEMM. 688 blocks (ks = bid&7 -> same-ks blocks co-XCD for
// x/L2 locality). Double-buffered LDS + register prefetch of chunk i+1
// issued BEFORE consuming chunk i; raw `s_waitcnt lgkmcnt(0); s_barrier`
// keeps the prefetch's vmcnt in flight across the barrier (a __syncthreads
// would drain vmcnt(0) and re-serialize the loads — m97/m131 evidence).
// Dequant identical to R4 (exact: 2^23 or-trick + Sterbenz subtract).
template<bool ATOMIC>
__global__ __launch_bounds__(256, 2) void gptq_gemm_kernel(
    const float* __restrict__ x, const int* __restrict__ qw,
    const int* __restrict__ qz, const float* __restrict__ scales,
    float* __restrict__ out)
{
  __shared__ int As[2 * ABUF];   // 10.2 KB
  __shared__ int Bs[2 * BBUF];   // 20.5 KB

  const int tid  = threadIdx.x;
  const int wave = tid >> 6;
  const int lane = tid & 63;
  const int c    = lane & 15;
  const int quad = lane >> 4;

  const int ks     = blockIdx.x & 7;
  const int ntile  = blockIdx.x >> 3;
  const int n0     = ntile * BN;
  const int kbase0 = ks * KSEG;

  const int am   = tid >> 2;          // A staging row 0..63
  const int aseg = tid & 3;           // A staging 8-k unit 0..3
  const int bu   = tid & 3;           // B staging qw row offset 0..3
  const int cp   = tid >> 2;          // B staging col-pair 0..63
  const int Ncp  = n0 + 2 * cp;
  const int mrow = wave * 16 + quad * 4;

  const float* xrow = x + am * KK + aseg * 8;

  f32x4 acc[8];
  #pragma unroll
  for (int t = 0; t < 8; ++t) acc[t] = {0.f, 0.f, 0.f, 0.f};

  // prefetch register sets (indexed by compile-time slot after full unroll)
  f32x4 pA0[2], pA1[2];
  i32x2 pB[2];
  f32x2 pS[2];
  int   pZ[2];

  auto pf = [&](int i, int sl) {
    const int kc = kbase0 + i * BK;
    pA0[sl] = *(const f32x4*)(xrow + kc);
    pA1[sl] = *(const f32x4*)(xrow + kc + 4);
    const int g  = kc >> 7;
    const int r0 = kc >> 3;
    pB[sl] = *(const i32x2*)(qw + (size_t)(r0 + bu) * NN + Ncp);
    pS[sl] = *(const f32x2*)(scales + g * NN + Ncp);
    pZ[sl] = qz[g * NZROW + (Ncp >> 3)];
  };

  pf(0, 0);

  #pragma unroll
  for (int i = 0; i < NCH; ++i) {
    const int sl = i & 1;
    if (i + 1 < NCH) pf(i + 1, sl ^ 1);   // issue early; overlaps everything below

    // ---- stage A: fp32 -> bf16 pairs ----
    int* Abuf = As + sl * ABUF;
    i32x4 pa;
    pa.x = pack_bf16(pA0[sl].x, pA0[sl].y);
    pa.y = pack_bf16(pA0[sl].z, pA0[sl].w);
    pa.z = pack_bf16(pA1[sl].x, pA1[sl].y);
    pa.w = pack_bf16(pA1[sl].z, pA1[sl].w);
    *(i32x4*)&Abuf[am * RS + aseg * 4] = pa;

    // ---- stage B: 2 adjacent cols, 8 k each, exact dequant ----
    int* Bbuf = Bs + sl * BBUF;
    const float s0 = pS[sl].x, s1 = pS[sl].y;
    const int sh0 = (Ncp & 7) * 4;             // Ncp even -> sh0+4 also valid
    const int z0  = (pZ[sl] >> sh0) & 15;
    const int z1  = (pZ[sl] >> (sh0 + 4)) & 15;
    const float C0 = (float)(0x800000 + z0 + 1);
    const float C1 = (float)(0x800000 + z1 + 1);
    const int v0 = pB[sl].x, v1 = pB[sl].y;
    i32x4 pb0, pb1;
    pb0.x = pack_bf16(s0 * (__int_as_float(((v0      ) & 15) | 0x4B000000) - C0),
                      s0 * (__int_as_float(((v0 >>  4) & 15) | 0x4B000000) - C0));
    pb0.y = pack_bf16(s0 * (__int_as_float(((v0 >>  8) & 15) | 0x4B000000) - C0),
                      s0 * (__int_as_float(((v0 >> 12) & 15) | 0x4B000000) - C0));
    pb0.z = pack_bf16(s0 * (__int_as_float(((v0 >> 16) & 15) | 0x4B000000) - C0),
                      s0 * (__int_as_float(((v0 >> 20) & 15) | 0x4B000000) - C0));
    pb0.w = pack_bf16(s0 * (__int_as_float(((v0 >> 24) & 15) | 0x4B000000) - C0),
                      s0 * (__int_as_float(((v0 >> 28) & 15) | 0x4B000000) - C0));
    pb1.x = pack_bf16(s1 * (__int_as_float(((v1      ) & 15) | 0x4B000000) - C1),
                      s1 * (__int_as_float(((v1 >>  4) & 15) | 0x4B000000) - C1));
    pb1.y = pack_bf16(s1 * (__int_as_float(((v1 >>  8) & 15) | 0x4B000000) - C1),
                      s1 * (__int_as_float(((v1 >> 12) & 15) | 0x4B000000) - C1));
    pb1.z = pack_bf16(s1 * (__int_as_float(((v1 >> 16) & 15) | 0x4B000000) - C1),
                      s1 * (__int_as_float(((v1 >> 20) & 15) | 0x4B000000) - C1));
    pb1.w = pack_bf16(s1 * (__int_as_float(((v1 >> 24) & 15) | 0x4B000000) - C1),
                      s1 * (__int_as_float(((v1 >> 28) & 15) | 0x4B000000) - C1));
    *(i32x4*)&Bbuf[(2 * cp    ) * RS + bu * 4] = pb0;
    *(i32x4*)&Bbuf[(2 * cp + 1) * RS + bu * 4] = pb1;

    // LDS-only barrier: leaves prefetch vmcnt outstanding
    __asm__ volatile("s_waitcnt lgkmcnt(0)\n\ts_barrier" ::: "memory");

    // ---- 8 MFMAs from this buffer (double-buffered: no trailing barrier) ----
    const s16x8 af = *(const s16x8*)&Abuf[(wave * 16 + c) * RS + quad * 4];
    #pragma unroll
    for (int t = 0; t < 8; ++t) {
      const s16x8 bfr = *(const s16x8*)&Bbuf[(t * 16 + c) * RS + quad * 4];
      acc[t] = __builtin_amdgcn_mfma_f32_16x16x32_bf16(af, bfr, acc[t], 0, 0, 0);
    }
  }

  // ---- epilogue ----
  if (ATOMIC) {
    #pragma unroll
    for (int t = 0; t < 8; ++t) {
      const int N = n0 + t * 16 + c;
      atomicAdd(&out[(mrow + 0) * NN + N], acc[t].x);
      atomicAdd(&out[(mrow + 1) * NN + N], acc[t].y);
      atomicAdd(&out[(mrow + 2) * NN + N], acc[t].z);
      atomicAdd(&out[(mrow + 3) * NN + N], acc[t].w);
    }
  } else {
    float* wsp = out + (size_t)ks * (MM * NN);
    #pragma unroll
    for (int t = 0; t < 8; ++t) {
      const int N = n0 + t * 16 + c;
      wsp[(mrow + 0) * NN + N] = acc[t].x;
      wsp[(mrow + 1) * NN + N] = acc[t].y;
      wsp[(mrow + 2) * NN + N] = acc[t].z;
      wsp[(mrow + 3) * NN + N] = acc[t].w;
    }
  }
}

} // namespace

extern "C" void kernel_launch(void* const* d_in, const int* in_sizes, int n_in,
                              void* d_out, int out_size, void* d_ws, size_t ws_size,
                              hipStream_t stream) {
  const float* x      = (const float*)d_in[0];
  const int*   qw     = (const int*)d_in[1];
  const int*   qz     = (const int*)d_in[2];
  const float* scales = (const float*)d_in[3];
  const float* bias   = (const float*)d_in[4];
  float* out = (float*)d_out;

  if (ws_size >= WS_NEED) {
    float* ws = (float*)d_ws;
    gptq_gemm_kernel<false><<<NTILES * KSPLIT, 256, 0, stream>>>(x, qw, qz, scales, ws);
    reduce_kernel<<<(MM * NN) / 1024, 256, 0, stream>>>(ws, bias, out);
  } else {
    prep_kernel<<<(MM * NN) / 256, 256, 0, stream>>>(bias, out);
    gptq_gemm_kernel<true><<<NTILES * KSPLIT, 256, 0, stream>>>(x, qw, qz, scales, out);
  }
}

// Round 6
// 96.438 us; speedup vs baseline: 1.2039x; 1.0081x over previous
//
#include <hip/hip_runtime.h>
#include <hip/hip_bf16.h>

namespace {

constexpr int MM = 64;
constexpr int KK = 4096;
constexpr int NN = 11008;
constexpr int NZROW = NN / 8;     // 1376
constexpr int BN = 128;           // cols per block tile
constexpr int KSPLIT = 8;
constexpr int KSEG = KK / KSPLIT; // 512
constexpr int NTILES = NN / BN;   // 86
constexpr int BK = 32;            // k per chunk (one MFMA K)
constexpr int NCH = KSEG / BK;    // 16 chunks
constexpr int RS = 20;            // LDS row stride in int32 (16 data + 4 pad, rows 16B aligned)
constexpr int ABUF = MM * RS;     // 1280 int32 per buffer
constexpr int BBUF = BN * RS;     // 2560 int32 per buffer
constexpr size_t WS_NEED = (size_t)KSPLIT * MM * NN * 4;  // 22.5 MB partials

typedef float f32x4 __attribute__((ext_vector_type(4)));
typedef float f32x2 __attribute__((ext_vector_type(2)));
typedef short s16x8 __attribute__((ext_vector_type(8)));
typedef int   i32x4 __attribute__((ext_vector_type(4)));
typedef int   i32x2 __attribute__((ext_vector_type(2)));

__device__ __forceinline__ int pack_bf16(float a, float b) {
  union { __hip_bfloat162 h; int i; } u;
  u.h.x = __float2bfloat16(a);
  u.h.y = __float2bfloat16(b);
  return u.i;
}

// fallback path only: out[m][n] = bias[n], atomics on top
__global__ __launch_bounds__(256) void prep_kernel(
    const float* __restrict__ bias, float* __restrict__ out)
{
  const int i = blockIdx.x * 256 + threadIdx.x;
  out[i] = bias[i % NN];
}

// ws path: out = bias + sum of KSPLIT partials
__global__ __launch_bounds__(256) void reduce_kernel(
    const float* __restrict__ ws, const float* __restrict__ bias,
    float* __restrict__ out)
{
  const int i4 = (blockIdx.x * 256 + threadIdx.x) * 4;
  f32x4 acc = *(const f32x4*)(bias + (i4 % NN));   // i4, NN multiples of 4
  #pragma unroll
  for (int s = 0; s < KSPLIT; ++s)
    acc += *(const f32x4*)(ws + (size_t)s * (MM * NN) + i4);
  *(f32x4*)(out + i4) = acc;
}

// Pipelined GPTQ GEMM, R6: occupancy 4 blocks/CU + depth-2 qw prefetch.
// In-flight math: 6 TB/s x 375 ns latency needs ~2.25 MB outstanding;
// 4 blk/CU x 4 waves x 512 B x depth2 ~= 4 MB -> HBM-limited, not
// latency-limited. LDS-only barrier (s_waitcnt lgkmcnt(0); s_barrier)
// keeps prefetch vmcnt in flight across it (verified correct in R5).
template<bool ATOMIC>
__global__ __launch_bounds__(256, 4) void gptq_gemm_kernel(
    const float* __restrict__ x, const int* __restrict__ qw,
    const int* __restrict__ qz, const float* __restrict__ scales,
    float* __restrict__ out)
{
  __shared__ int As[2 * ABUF];   // 10.2 KB
  __shared__ int Bs[2 * BBUF];   // 20.5 KB

  const int tid  = threadIdx.x;
  const int wave = tid >> 6;
  const int lane = tid & 63;
  const int c    = lane & 15;
  const int quad = lane >> 4;

  const int ks     = blockIdx.x & 7;
  const int ntile  = blockIdx.x >> 3;
  const int n0     = ntile * BN;
  const int kbase0 = ks * KSEG;

  const int am   = tid >> 2;          // A staging row 0..63
  const int aseg = tid & 3;           // A staging 8-k unit 0..3
  const int bu   = tid & 3;           // B staging qw row offset 0..3
  const int cp   = tid >> 2;          // B staging col-pair 0..63
  const int Ncp  = n0 + 2 * cp;
  const int mrow = wave * 16 + quad * 4;

  const float* xrow = x + am * KK + aseg * 8;

  f32x4 acc[8];
  #pragma unroll
  for (int t = 0; t < 8; ++t) acc[t] = {0.f, 0.f, 0.f, 0.f};

  // rotating prefetch registers (indices fold after full unroll)
  f32x4 pA0[2], pA1[2];   // x, depth-1 (L2-warm across same-ks blocks)
  f32x2 pS[2];            // scales, depth-1 (L3-warm)
  int   pZ[2];            // qzeros, depth-1
  i32x2 pB[3];            // qweight, depth-2 (cold HBM stream)

  auto pfA = [&](int i) {
    const int sl = i & 1;
    const int kc = kbase0 + i * BK;
    pA0[sl] = *(const f32x4*)(xrow + kc);
    pA1[sl] = *(const f32x4*)(xrow + kc + 4);
    const int g = kc >> 7;
    pS[sl] = *(const f32x2*)(scales + g * NN + Ncp);
    pZ[sl] = qz[g * NZROW + (Ncp >> 3)];
  };
  auto pfB = [&](int i) {
    const int kc = kbase0 + i * BK;
    pB[i % 3] = *(const i32x2*)(qw + (size_t)((kc >> 3) + bu) * NN + Ncp);
  };

  pfB(0); pfB(1); pfA(0);

  #pragma unroll
  for (int i = 0; i < NCH; ++i) {
    const int sl = i & 1;
    if (i + 2 < NCH) pfB(i + 2);    // deep qw prefetch
    if (i + 1 < NCH) pfA(i + 1);    // x/scale/zero prefetch

    // ---- stage A: fp32 -> bf16 pairs ----
    int* Abuf = As + sl * ABUF;
    i32x4 pa;
    pa.x = pack_bf16(pA0[sl].x, pA0[sl].y);
    pa.y = pack_bf16(pA0[sl].z, pA0[sl].w);
    pa.z = pack_bf16(pA1[sl].x, pA1[sl].y);
    pa.w = pack_bf16(pA1[sl].z, pA1[sl].w);
    *(i32x4*)&Abuf[am * RS + aseg * 4] = pa;

    // ---- stage B: 2 adjacent cols x 8 k, exact dequant ----
    // qf = (nib | 0x4B000000) = 2^23 + q exactly; subtract C = 2^23+z+1
    // (Sterbenz-exact integer q-z-1); single rounding in s*d.
    int* Bbuf = Bs + sl * BBUF;
    const float s0 = pS[sl].x, s1 = pS[sl].y;
    const int sh0 = (Ncp & 7) * 4;
    const int z0  = (pZ[sl] >> sh0) & 15;
    const int z1  = (pZ[sl] >> (sh0 + 4)) & 15;
    const float C0 = (float)(0x800000 + z0 + 1);
    const float C1 = (float)(0x800000 + z1 + 1);
    const int v0 = pB[i % 3].x, v1 = pB[i % 3].y;
    i32x4 pb0, pb1;
    pb0.x = pack_bf16(s0 * (__int_as_float(((v0      ) & 15) | 0x4B000000) - C0),
                      s0 * (__int_as_float(((v0 >>  4) & 15) | 0x4B000000) - C0));
    pb0.y = pack_bf16(s0 * (__int_as_float(((v0 >>  8) & 15) | 0x4B000000) - C0),
                      s0 * (__int_as_float(((v0 >> 12) & 15) | 0x4B000000) - C0));
    pb0.z = pack_bf16(s0 * (__int_as_float(((v0 >> 16) & 15) | 0x4B000000) - C0),
                      s0 * (__int_as_float(((v0 >> 20) & 15) | 0x4B000000) - C0));
    pb0.w = pack_bf16(s0 * (__int_as_float(((v0 >> 24) & 15) | 0x4B000000) - C0),
                      s0 * (__int_as_float(((v0 >> 28) & 15) | 0x4B000000) - C0));
    pb1.x = pack_bf16(s1 * (__int_as_float(((v1      ) & 15) | 0x4B000000) - C1),
                      s1 * (__int_as_float(((v1 >>  4) & 15) | 0x4B000000) - C1));
    pb1.y = pack_bf16(s1 * (__int_as_float(((v1 >>  8) & 15) | 0x4B000000) - C1),
                      s1 * (__int_as_float(((v1 >> 12) & 15) | 0x4B000000) - C1));
    pb1.z = pack_bf16(s1 * (__int_as_float(((v1 >> 16) & 15) | 0x4B000000) - C1),
                      s1 * (__int_as_float(((v1 >> 20) & 15) | 0x4B000000) - C1));
    pb1.w = pack_bf16(s1 * (__int_as_float(((v1 >> 24) & 15) | 0x4B000000) - C1),
                      s1 * (__int_as_float(((v1 >> 28) & 15) | 0x4B000000) - C1));
    *(i32x4*)&Bbuf[(2 * cp    ) * RS + bu * 4] = pb0;
    *(i32x4*)&Bbuf[(2 * cp + 1) * RS + bu * 4] = pb1;

    // LDS-only barrier: leaves prefetch vmcnt outstanding
    __asm__ volatile("s_waitcnt lgkmcnt(0)\n\ts_barrier" ::: "memory");

    // ---- 8 MFMAs from this buffer (dbuf: no trailing barrier needed) ----
    const s16x8 af = *(const s16x8*)&Abuf[(wave * 16 + c) * RS + quad * 4];
    #pragma unroll
    for (int t = 0; t < 8; ++t) {
      const s16x8 bfr = *(const s16x8*)&Bbuf[(t * 16 + c) * RS + quad * 4];
      acc[t] = __builtin_amdgcn_mfma_f32_16x16x32_bf16(af, bfr, acc[t], 0, 0, 0);
    }
  }

  // ---- epilogue ----
  if (ATOMIC) {
    #pragma unroll
    for (int t = 0; t < 8; ++t) {
      const int N = n0 + t * 16 + c;
      atomicAdd(&out[(mrow + 0) * NN + N], acc[t].x);
      atomicAdd(&out[(mrow + 1) * NN + N], acc[t].y);
      atomicAdd(&out[(mrow + 2) * NN + N], acc[t].z);
      atomicAdd(&out[(mrow + 3) * NN + N], acc[t].w);
    }
  } else {
    float* wsp = out + (size_t)ks * (MM * NN);
    #pragma unroll
    for (int t = 0; t < 8; ++t) {
      const int N = n0 + t * 16 + c;
      wsp[(mrow + 0) * NN + N] = acc[t].x;
      wsp[(mrow + 1) * NN + N] = acc[t].y;
      wsp[(mrow + 2) * NN + N] = acc[t].z;
      wsp[(mrow + 3) * NN + N] = acc[t].w;
    }
  }
}

} // namespace

extern "C" void kernel_launch(void* const* d_in, const int* in_sizes, int n_in,
                              void* d_out, int out_size, void* d_ws, size_t ws_size,
                              hipStream_t stream) {
  const float* x      = (const float*)d_in[0];
  const int*   qw     = (const int*)d_in[1];
  const int*   qz     = (const int*)d_in[2];
  const float* scales = (const float*)d_in[3];
  const float* bias   = (const float*)d_in[4];
  float* out = (float*)d_out;

  if (ws_size >= WS_NEED) {
    float* ws = (float*)d_ws;
    gptq_gemm_kernel<false><<<NTILES * KSPLIT, 256, 0, stream>>>(x, qw, qz, scales, ws);
    reduce_kernel<<<(MM * NN) / 1024, 256, 0, stream>>>(ws, bias, out);
  } else {
    prep_kernel<<<(MM * NN) / 256, 256, 0, stream>>>(bias, out);
    gptq_gemm_kernel<true><<<NTILES * KSPLIT, 256, 0, stream>>>(x, qw, qz, scales, out);
  }
}